// Round 17
// baseline (87.226 us; speedup 1.0000x reference)
//
#include <hip/hip_runtime.h>

// Problem constants
#define BB 16
#define NN 512
#define HH 128
#define SB 32   // sinkhorn slabs (blocks) per batch
#define RB 16   // sinkhorn rows per slab

#define SCOPE_AGENT __HIP_MEMORY_SCOPE_AGENT

typedef _Float16 f16x8 __attribute__((ext_vector_type(8)));
typedef _Float16 f16x4 __attribute__((ext_vector_type(4)));
typedef _Float16 f16x2 __attribute__((ext_vector_type(2)));
typedef float    f32x4 __attribute__((ext_vector_type(4)));

// ------------------------------------------------------------ fused GCN ----
// R16-proven math (ping-pong staging, 1 barrier/K-step; Cl parked *2^-10
// against f16 overflow; layer 1 writes f16 adjacency for layers 2/3).
// NEW (R17): layer 1 also writes WT2/WT3 (f16 W, transposed [n][k]) to ws;
// layers 2/3 read phase-2 W fragments DIRECTLY from WT (L2-resident 32 KB)
// -> no 64-rep Wl prologue (8-way-conflicted LDS writes), -34 KB LDS.
template <bool EMB>
__global__ __launch_bounds__(256) void gcn_kernel(
    const float* __restrict__ dist, _Float16* __restrict__ adjws,
    const _Float16* __restrict__ xTin,
    const float* __restrict__ pts, const float* __restrict__ Wemb,
    const float* __restrict__ bemb,
    const float* __restrict__ W, const float* __restrict__ bias,
    const float* __restrict__ W2g, const float* __restrict__ W3g,
    _Float16* __restrict__ WT2, _Float16* __restrict__ WT3,
    const _Float16* __restrict__ WTin,
    _Float16* __restrict__ xfout, _Float16* __restrict__ xTout,
    unsigned int* __restrict__ ctrlz)
{
  __shared__ _Float16 Al2[2][16][40];   // adj tile (f16), bank-spread
  __shared__ _Float16 Bl2[2][128][40];  // x^T tile
  __shared__ _Float16 Cl[16][136];      // nb tile * 2^-10 (phase-1 result)
  __shared__ _Float16 Wl[EMB ? 128 : 1][136];  // W^T (layer 1 only)

  const int bid = blockIdx.x;
  const int mt = bid & 31, b = bid >> 5;
  const int tid = threadIdx.x;
  const int row0 = mt * 16;

  if (EMB) {  // fold ctrl zeroing + WT2/WT3 transpose into layer 1
    int gid = bid * 256 + tid;
    if (gid < 49152) ctrlz[gid] = 0u;
    if (gid < 16384) {
      const int k = gid >> 7, n = gid & 127;
      WT2[(size_t)n * HH + k] = (_Float16)W2g[gid];  // W2g[k*128+n]
      WT3[(size_t)n * HH + k] = (_Float16)W3g[gid];
    }
    // stage W1 transposed into LDS (128x128 = 16384 / 256 thr = 64 reps)
    #pragma unroll
    for (int rep = 0; rep < 64; ++rep) {
      const int idx = rep * 256 + tid;
      const int k = idx >> 7, n = idx & 127;
      Wl[n][k] = (_Float16)W[(size_t)k * HH + n];
    }
  }

  const float* Ab = dist + ((size_t)b * NN + row0) * NN;
  _Float16* adjwb = adjws + ((size_t)b * NN + row0) * NN;         // layer 1 out
  const _Float16* adjrb = adjws + ((size_t)b * NN + row0) * NN;   // layers 2/3 in
  const _Float16* xTb = EMB ? nullptr : (xTin + (size_t)b * HH * NN);

  const int wv = tid >> 6, lane = tid & 63;
  const int fr = lane & 15, fo = lane >> 4;

  // EMB: hoist per-h weights (thread handles h-rows n0 and n0+64)
  float we0a = 0.f, we1a = 0.f, ba = 0.f, we0b = 0.f, we1b = 0.f, bb2 = 0.f;
  const int n0 = tid >> 2, q4 = tid & 3;
  if (EMB) {
    we0a = Wemb[n0];      we1a = Wemb[HH + n0];      ba  = bemb[n0];
    we0b = Wemb[n0 + 64]; we1b = Wemb[HH + n0 + 64]; bb2 = bemb[n0 + 64];
  }

  // ---- staging lambdas (write into buffer `buf` for K-chunk k0) ----
  auto stageA = [&](int buf, int k0) {
    const int r = tid >> 4, q = tid & 15;   // 16 rows x 16 pairs = 512 f16
    if (EMB) {  // f32 dist -> exp(-x) -> f16 (+ store adj16 for layers 2/3)
      float2 v = *reinterpret_cast<const float2*>(&Ab[(size_t)r * NN + k0 + q * 2]);
      f16x2 h;
      h[0] = (_Float16)__expf(-v.x); h[1] = (_Float16)__expf(-v.y);
      *reinterpret_cast<f16x2*>(&Al2[buf][r][q * 2]) = h;
      *reinterpret_cast<f16x2*>(&adjwb[(size_t)r * NN + k0 + q * 2]) = h;
    } else {    // direct f16 adjacency load
      *reinterpret_cast<f16x2*>(&Al2[buf][r][q * 2]) =
          *reinterpret_cast<const f16x2*>(&adjrb[(size_t)r * NN + k0 + q * 2]);
    }
  };
  auto stageB = [&](int buf, int k0) {
    if (!EMB) {  // from xT rows (contig k)
      #pragma unroll
      for (int it = 0; it < 2; ++it) {
        const int slot = it * 256 + tid;
        const int n = slot >> 2, q = slot & 3;
        f16x8 v = *reinterpret_cast<const f16x8*>(&xTb[(size_t)n * NN + k0 + q * 8]);
        *reinterpret_cast<f16x8*>(&Bl2[buf][n][q * 8]) = v;
      }
    } else {     // x0^T computed on the fly
      float2 pv[8];
      #pragma unroll
      for (int e = 0; e < 8; ++e)
        pv[e] = *reinterpret_cast<const float2*>(
            &pts[((size_t)b * NN + k0 + q4 * 8 + e) * 2]);
      f16x8 va, vb;
      #pragma unroll
      for (int e = 0; e < 8; ++e) {
        va[e] = (_Float16)fmaf(pv[e].x, we0a, fmaf(pv[e].y, we1a, ba));
        vb[e] = (_Float16)fmaf(pv[e].x, we0b, fmaf(pv[e].y, we1b, bb2));
      }
      *reinterpret_cast<f16x8*>(&Bl2[buf][n0][q4 * 8]) = va;
      *reinterpret_cast<f16x8*>(&Bl2[buf][n0 + 64][q4 * 8]) = vb;
    }
  };

  f32x4 acc[2] = {};

  stageA(0, 0);
  stageB(0, 0);
  __syncthreads();

  for (int k0 = 0; k0 < NN; k0 += 32) {
    const int cur = (k0 >> 5) & 1;
    if (k0 + 32 < NN) {        // stage next chunk into the other buffer
      stageA(cur ^ 1, k0 + 32);
      stageB(cur ^ 1, k0 + 32);
    }
    f16x8 af = *reinterpret_cast<const f16x8*>(&Al2[cur][fr][fo * 8]);
    #pragma unroll
    for (int nt = 0; nt < 2; ++nt) {
      f16x8 bf = *reinterpret_cast<const f16x8*>(&Bl2[cur][wv * 32 + nt * 16 + fr][fo * 8]);
      acc[nt] = __builtin_amdgcn_mfma_f32_16x16x32_f16(af, bf, acc[nt], 0, 0, 0);
    }
    __syncthreads();  // next-stage writes landed; everyone done reading cur
  }

  // park nb tile in LDS, scaled 2^-10 (exact) to stay inside f16 range
  #pragma unroll
  for (int nt = 0; nt < 2; ++nt) {
    const int col = wv * 32 + nt * 16 + fr;
    #pragma unroll
    for (int m = 0; m < 4; ++m)
      Cl[fo * 4 + m][col] = (_Float16)(acc[nt][m] * 0x1p-10f);
  }
  __syncthreads();

  // phase 2: out = relu((nb_scaled @ W) * 2^10 + bias)
  // B-fragments: layer 1 from LDS Wl; layers 2/3 straight from WT (L2).
  f32x4 acc2[2] = {};
  #pragma unroll
  for (int ks = 0; ks < 4; ++ks) {
    f16x8 af2 = *reinterpret_cast<const f16x8*>(&Cl[fr][ks * 32 + fo * 8]);
    #pragma unroll
    for (int nt = 0; nt < 2; ++nt) {
      const int col = wv * 32 + nt * 16 + fr;
      f16x8 bf2;
      if (EMB)
        bf2 = *reinterpret_cast<const f16x8*>(&Wl[col][ks * 32 + fo * 8]);
      else
        bf2 = *reinterpret_cast<const f16x8*>(&WTin[(size_t)col * HH + ks * 32 + fo * 8]);
      acc2[nt] = __builtin_amdgcn_mfma_f32_16x16x32_f16(af2, bf2, acc2[nt], 0, 0, 0);
    }
  }

  _Float16* xfb = xfout + (size_t)b * NN * HH;
  _Float16* xTb2 = xTout + (size_t)b * HH * NN;
  #pragma unroll
  for (int nt = 0; nt < 2; ++nt) {
    const int col = wv * 32 + nt * 16 + fr;
    const float bv = bias[col];
    const int rowb = row0 + fo * 4;
    f16x4 hc;
    #pragma unroll
    for (int m = 0; m < 4; ++m) {
      float v = fmaxf(fmaf(acc2[nt][m], 1024.0f, bv), 0.0f);
      hc[m] = (_Float16)v;
      xfb[(size_t)(rowb + m) * HH + col] = (_Float16)v;
    }
    *reinterpret_cast<f16x4*>(&xTb2[(size_t)col * NN + rowb]) = hc;
  }
}

// ----------------------------------------------------------- Sinkhorn ------
// R16-PROVEN, byte-identical (fused logits prologue, 32 distributed flags
// w/ vote-in-flag early exit, agent-scope relaxed atomics, delta-trick
// accumulators, eps=2e-3).
__global__ __launch_bounds__(256) void sinkhorn_kernel(
    const _Float16* __restrict__ xf, const float* __restrict__ noise,
    float* __restrict__ cacc, unsigned int* __restrict__ flags,
    float* __restrict__ out)
{
  __shared__ float Pl[RB][513];
  __shared__ float cl[512];
  __shared__ float rl[RB];
  __shared__ float red[16][17];
  __shared__ float wmax[4];
  __shared__ int stopf;

  const int bid = blockIdx.x;
  const int b = bid >> 5, s = bid & 31;
  const int tid = threadIdx.x;
  const int i0 = s * RB;

  const _Float16* xb = xf + (size_t)b * NN * HH;
  const float* nzb = noise + ((size_t)b * NN + i0) * NN;
  const int wv = tid >> 6, lane = tid & 63;
  const int fr = lane & 15, fo = lane >> 4;
  const int jbase = wv * 128;

  // ---- fused logits -> P0 tile (16 rows x 512 cols) ----
  {
    f16x8 af[4];
    #pragma unroll
    for (int ks = 0; ks < 4; ++ks)
      af[ks] = *reinterpret_cast<const f16x8*>(
          &xb[(size_t)(i0 + fr) * HH + ks * 32 + fo * 8]);

    float rowpart[4] = {0.f, 0.f, 0.f, 0.f};
    for (int jt = 0; jt < 8; ++jt) {
      const int jcol = jbase + jt * 16 + fr;
      f32x4 acc = {};
      #pragma unroll
      for (int ks = 0; ks < 4; ++ks) {
        f16x8 bf = *reinterpret_cast<const f16x8*>(
            &xb[(size_t)jcol * HH + ks * 32 + fo * 8]);
        acc = __builtin_amdgcn_mfma_f32_16x16x32_f16(af[ks], bf, acc, 0, 0, 0);
      }
      #pragma unroll
      for (int m = 0; m < 4; ++m) {
        const int r = fo * 4 + m;
        float sv = acc[m];
        if (i0 + r == jcol) sv -= 1e9f;
        float th = 1.0f - 2.0f / (__expf(2.0f * sv) + 1.0f);   // tanh
        float u  = nzb[(size_t)r * NN + jcol];
        float eps = -__logf(-__logf(u));                        // Gumbel
        float e = __expf((10.0f * th + 0.01f * eps) * (1.0f / 3.0f));
        Pl[r][jcol] = e;
        rowpart[m] += e;
      }
    }
    #pragma unroll
    for (int m = 0; m < 4; ++m) {
      float v = rowpart[m];
      v += __shfl_xor(v, 1); v += __shfl_xor(v, 2);
      v += __shfl_xor(v, 4); v += __shfl_xor(v, 8);
      if (fr == 0) red[wv][fo * 4 + m] = v;
    }
  }
  cl[tid] = 1.0f; cl[tid + 256] = 1.0f;
  __syncthreads();
  if (tid < RB)
    rl[tid] = 1.0f / (red[0][tid] + red[1][tid] + red[2][tid] + red[3][tid]);
  __syncthreads();

  auto row_update = [&]() {
    const int i = tid & 15, ch = tid >> 4;
    const int j0 = ch * 32, st = (ch * 8) & 31;
    float p = 0.0f;
    #pragma unroll
    for (int q = 0; q < 32; ++q) {
      const int j = j0 + ((q + st) & 31);
      p = fmaf(Pl[i][j], cl[j], p);
    }
    red[ch][i] = p;
    __syncthreads();
    if (tid < RB) {
      float v = 0.0f;
      #pragma unroll
      for (int q = 0; q < 16; ++q) v += red[q][tid];
      rl[tid] = 1.0f / v;
    }
    __syncthreads();
  };

  unsigned int* myflag = flags + (size_t)(b * SB + s) * 64;
  float* ca0 = cacc + (size_t)b * 512;
  float* ca1 = cacc + (size_t)(BB + b) * 512;
  float pA0 = 0.f, pA1 = 0.f, pB0 = 0.f, pB1 = 0.f;
  unsigned int convbit = 0;

  for (int it = 0; it < 60; ++it) {
    float* ca  = (it & 1) ? ca1 : ca0;
    float& pv0 = (it & 1) ? pB0 : pA0;
    float& pv1 = (it & 1) ? pB1 : pA1;

    // phase A: partial column sums of diag(r)P0 over this slab -> atomicAdd
    float u0 = 0.0f, u1 = 0.0f;
    #pragma unroll
    for (int i2 = 0; i2 < RB; ++i2) {
      const float rv = rl[i2];
      u0 = fmaf(Pl[i2][tid],       rv, u0);
      u1 = fmaf(Pl[i2][tid + 256], rv, u1);
    }
    __hip_atomic_fetch_add(&ca[tid],       u0 - pv0, __ATOMIC_RELAXED, SCOPE_AGENT);
    __hip_atomic_fetch_add(&ca[tid + 256], u1 - pv1, __ATOMIC_RELAXED, SCOPE_AGENT);
    pv0 = u0; pv1 = u1;
    __syncthreads();  // vmcnt(0): this block's adds acked at coherence point

    // arrive: monotonic flag carries the convergence vote in bit 0
    if (tid == 0)
      __hip_atomic_store(myflag, ((unsigned int)(it + 1) << 1) | convbit,
                         __ATOMIC_RELAXED, SCOPE_AGENT);
    // wait (wave 0): 32 lanes poll the 32 flags; AND the votes via ballot
    if (tid < 64) {
      unsigned int v = 3u;              // lanes 32..63: arrived + vote yes
      if (tid < SB) {
        const unsigned int* fp = flags + (size_t)(b * SB + tid) * 64;
        do {
          v = __hip_atomic_load(fp, __ATOMIC_RELAXED, SCOPE_AGENT);
          if ((v >> 1) >= (unsigned int)(it + 1)) break;
          __builtin_amdgcn_s_sleep(1);
        } while (true);
      }
      unsigned long long m = __ballot((v & 1u) != 0u);
      if (tid == 0) stopf = ((m & 0xFFFFFFFFull) == 0xFFFFFFFFull) ? 1 : 0;
    }
    __syncthreads();
    if (stopf) break;   // unanimous: derived from the same 32 published words

    // phase B: read summed colsums; measure dm; update c; row pass
    float t0 = __hip_atomic_load(&ca[tid],       __ATOMIC_RELAXED, SCOPE_AGENT);
    float t1 = __hip_atomic_load(&ca[tid + 256], __ATOMIC_RELAXED, SCOPE_AGENT);
    float d = fmaxf(fabsf(fmaf(t0, cl[tid], -1.0f)),
                    fabsf(fmaf(t1, cl[tid + 256], -1.0f)));
    #pragma unroll
    for (int off = 32; off >= 1; off >>= 1) d = fmaxf(d, __shfl_xor(d, off));
    if ((tid & 63) == 0) wmax[tid >> 6] = d;
    cl[tid] = 1.0f / t0; cl[tid + 256] = 1.0f / t1;
    __syncthreads();
    const float dm = fmaxf(fmaxf(wmax[0], wmax[1]), fmaxf(wmax[2], wmax[3]));
    convbit = (dm < 2e-3f) ? 1u : 0u;
    row_update();
  }

  // final: out = r_i * P0_ij * c_j   (float4, reads LDS only)
  float* Ob = out + ((size_t)b * NN + i0) * NN;
  #pragma unroll
  for (int rep = 0; rep < 8; ++rep) {
    const int row = rep * 2 + (tid >> 7);     // 0..15
    const int c4  = (tid & 127) * 4;          // 0..508
    const float rv = rl[row];
    float4 o;
    o.x = rv * Pl[row][c4 + 0] * cl[c4 + 0];
    o.y = rv * Pl[row][c4 + 1] * cl[c4 + 1];
    o.z = rv * Pl[row][c4 + 2] * cl[c4 + 2];
    o.w = rv * Pl[row][c4 + 3] * cl[c4 + 3];
    *reinterpret_cast<float4*>(&Ob[(size_t)row * NN + c4]) = o;
  }
}

// ------------------------------------------------------------- launch ------
extern "C" void kernel_launch(void* const* d_in, const int* in_sizes, int n_in,
                              void* d_out, int out_size, void* d_ws, size_t ws_size,
                              hipStream_t stream)
{
  const float* points = (const float*)d_in[0];
  const float* dist   = (const float*)d_in[1];
  const float* noise  = (const float*)d_in[2];
  const float* Wemb   = (const float*)d_in[3];
  const float* bemb   = (const float*)d_in[4];
  const float* W1 = (const float*)d_in[5]; const float* b1 = (const float*)d_in[6];
  const float* W2 = (const float*)d_in[7]; const float* b2 = (const float*)d_in[8];
  const float* W3 = (const float*)d_in[9]; const float* b3 = (const float*)d_in[10];
  float* out = (float*)d_out;

  char* ws = (char*)d_ws;                              // ws_size = 256 MiB
  _Float16* xfA = (_Float16*)ws;                       // 2 MB
  _Float16* xTA = (_Float16*)(ws + (2u << 20));        // 2 MB
  _Float16* xfB = (_Float16*)(ws + (4u << 20));        // 2 MB
  _Float16* xTB = (_Float16*)(ws + (6u << 20));        // 2 MB
  _Float16* adjw = (_Float16*)(ws + (8u << 20));       // 8 MB (f16 adjacency)
  _Float16* WT2 = (_Float16*)(ws + (16u << 20));                 // 32 KB
  _Float16* WT3 = (_Float16*)(ws + (16u << 20) + (32u << 10));   // 32 KB
  char* ctrl = ws + (17u << 20);
  float*        cacc  = (float*)ctrl;                  // 64 KB
  unsigned int* flags = (unsigned int*)(ctrl + (64u << 10));  // 128 KB
  // ws usage: 17 MB + 192 KB << 256 MiB  ✓

  // 3 fused GCN layers, 512 blocks = 2/CU. Layer 1: embeds on the fly,
  // writes adj16 + WT2/WT3, zeroes ctrl. Layers 2/3: W from WT (no prologue).
  gcn_kernel<true><<<512, 256, 0, stream>>>(
      dist, adjw, nullptr, points, Wemb, bemb, W1, b1,
      W2, W3, WT2, WT3, nullptr, xfA, xTA, (unsigned int*)ctrl);
  gcn_kernel<false><<<512, 256, 0, stream>>>(
      nullptr, adjw, xTA, nullptr, nullptr, nullptr, nullptr, b2,
      nullptr, nullptr, nullptr, nullptr, WT2, xfB, xTB, nullptr);
  gcn_kernel<false><<<512, 256, 0, stream>>>(
      nullptr, adjw, xTB, nullptr, nullptr, nullptr, nullptr, b3,
      nullptr, nullptr, nullptr, nullptr, WT3, xfA, xTA, nullptr);

  // Sinkhorn (logits fused in prologue; proven barrier protocol; eps=2e-3)
  const _Float16* xfc = xfA; const float* nzc = noise;
  float* caccP = cacc; unsigned int* flagsP = flags; float* outP = out;
  void* args[] = {(void*)&xfc, (void*)&nzc, (void*)&caccP, (void*)&flagsP, (void*)&outP};
  hipLaunchCooperativeKernel(reinterpret_cast<void*>(sinkhorn_kernel),
                             dim3(BB * SB), dim3(256), args, 0, stream);
}